// Round 3
// baseline (1850.978 us; speedup 1.0000x reference)
//
#include <hip/hip_runtime.h>
#include <hip/hip_bf16.h>

#define LAT 128
#define H 256
#define OUTD 64
#define SEQ 512

typedef short bf16x8 __attribute__((ext_vector_type(8)));
typedef float f32x4  __attribute__((ext_vector_type(4)));
typedef unsigned long long u64;
typedef unsigned u32;

__device__ __forceinline__ float sigm(float x)  { return 1.f / (1.f + __expf(-x)); }
__device__ __forceinline__ float tanhf_(float x){ return 1.f - 2.f / (__expf(2.f * x) + 1.f); }

__device__ __forceinline__ short f2bs(float x) {
    __hip_bfloat16 b = __float2bfloat16(x);
    return *reinterpret_cast<short*>(&b);
}
__device__ __forceinline__ float bs2f(unsigned short h) {
    u32 b = ((u32)h) << 16;
    float f; __builtin_memcpy(&f, &b, 4); return f;
}
__device__ __forceinline__ u32 f2pair(float a, float b) {
    return ((u32)(unsigned short)f2bs(b) << 16) | (u32)(unsigned short)f2bs(a);
}
__device__ __forceinline__ bf16x8 pack8(const float* s) {
    bf16x8 v;
    v[0]=f2bs(s[0]); v[1]=f2bs(s[1]); v[2]=f2bs(s[2]); v[3]=f2bs(s[3]);
    v[4]=f2bs(s[4]); v[5]=f2bs(s[5]); v[6]=f2bs(s[6]); v[7]=f2bs(s[7]);
    return v;
}

// ---- Transport accessors: SYSTEM scope (round-0/1 proven stable transport).
// Round-2 lesson: agent scope + per-line-accept regressed (1592 us steady,
// one 32 ms outlier). Reverted to the proven system-scope reload-all protocol;
// this round attacks the SERIALIZED POLL LATENCY structurally instead.
__device__ __forceinline__ u64 sys_load_u64(const u64* p) {
    return __hip_atomic_load((u64*)p, __ATOMIC_RELAXED, __HIP_MEMORY_SCOPE_SYSTEM);
}
__device__ __forceinline__ void sys_store_u64(u64* p, u64 v) {
    __hip_atomic_store(p, v, __ATOMIC_RELAXED, __HIP_MEMORY_SCOPE_SYSTEM);
}

// ---------------- Prologue 1 (round-8 verbatim): tagged h-init, c-init, L1 bias ----
__global__ void lstm_prologue_init(const float* __restrict__ z,
                                   const float* __restrict__ Whid,
                                   const float* __restrict__ bhid,
                                   const float* __restrict__ Wcell,
                                   const float* __restrict__ bcell,
                                   const float* __restrict__ bih1,
                                   const float* __restrict__ bhh1,
                                   u64* __restrict__ h0B1,
                                   u64* __restrict__ h1B1,
                                   float* __restrict__ c0,
                                   float* __restrict__ c1,
                                   float* __restrict__ gxb1)
{
    int t = blockIdx.x * 256 + threadIdx.x;
    if (t < 65536) {                     // tagged hidden-init: 2 layers x 256 b x 128 pairs
        int layer = t >> 15;
        int tt = t & 32767;
        int b = tt >> 7, cp = tt & 127;
        int colA = layer * H + 2 * cp;
        const float* zr = z + b * LAT;
        const float* wA = Whid + colA * LAT;
        const float* wB = wA + LAT;
        float a0 = bhid[colA], a1 = bhid[colA + 1];
        for (int k = 0; k < LAT; k++) { float zv = zr[k]; a0 += zv * wA[k]; a1 += zv * wB[k]; }
        u64 v = ((u64)(u32)layer << 32) | (u64)f2pair(a0, a1);
        (layer ? h1B1 : h0B1)[b * 128 + cp] = v;
    } else if (t < 196608) {             // cell init: [256 x 512]
        int tt = t - 65536;
        int b = tt >> 9, col = tt & 511;
        const float* w  = Wcell + col * LAT;
        const float* zr = z + b * LAT;
        float acc = bcell[col];
        for (int k = 0; k < LAT; k++) acc += zr[k] * w[k];
        if (col < H) c0[b * H + col] = acc;
        else         c1[b * H + (col - H)] = acc;
    } else if (t < 197632) {             // layer-1 gate bias vector [1024]
        int g = t - 196608;
        gxb1[g] = bih1[g] + bhh1[g];
    }
}

// ---------------- Prologue 2 (round-8 verbatim): gx0 packed bf16 pairs ----
__global__ void lstm_prologue_gx0(const float* __restrict__ z,
                                  const float* __restrict__ Win,
                                  const float* __restrict__ bin,
                                  const float* __restrict__ Wih0,
                                  const float* __restrict__ bih0,
                                  const float* __restrict__ bhh0,
                                  u32* __restrict__ gxb0u)
{
    __shared__ float xs[H];
    const int b = blockIdx.y;
    const int tid = threadIdx.x;
    {
        const float* w  = Win + tid * LAT;
        const float* zr = z + b * LAT;
        float acc = bin[tid];
        for (int k = 0; k < LAT; k++) acc += zr[k] * w[k];
        xs[tid] = acc;
    }
    __syncthreads();
    const int cA = blockIdx.x * 512 + 2 * tid;
    const float* wA = Wih0 + cA * H;
    const float* wB = wA + H;
    float a0 = bih0[cA]     + bhh0[cA];
    float a1 = bih0[cA + 1] + bhh0[cA + 1];
    for (int k = 0; k < H; k++) { float xv = xs[k]; a0 += xv * wA[k]; a1 += xv * wB[k]; }
    gxb0u[b * 512 + blockIdx.x * 256 + tid] = f2pair(a0, a1);
}

// ---------------- Persistent kernel ----------------
// 256 wgs x 256 thr. Cluster bg = wg>>4, wg j = wg&15 owns 16 hidden cols.
// MERGED-POLL structure (round 3): one staging phase + ONE barrier per
// iteration (was two of each). h0 poll loads are issued LATE in the previous
// iteration (after the L1 publish, ~0.8T: all wgs' h0 publishes from ~0.4T
// are visible by then) and carried in registers across the loop boundary ->
// the top-of-iteration h0 check is register-only in the common case. h1 loads
// (least slack: published end of prev iter) are issued first thing at top so
// their latency overlaps h0 staging. Snapshot reload-all semantics retained
// for both (round-1-proven; no per-line accept).
// Parity-plane safety with a single barrier: stage-writes to plane par^1 at
// iter k+1 are after barrier(k), which is after all frag-reads of plane par^1
// at iter k-1 (program order: reads(k-1) -> top(k) -> barrier(k)).
__global__ __launch_bounds__(256, 1)
void lstm_persistent(const u32* __restrict__ gxb0u, const float* __restrict__ gxb1,
                     const float* __restrict__ c0g, const float* __restrict__ c1g,
                     u64* __restrict__ h0B0, u64* __restrict__ h0B1,
                     u64* __restrict__ h1B0, u64* __restrict__ h1B1,
                     const float* __restrict__ Whh0, const float* __restrict__ Wih1,
                     const float* __restrict__ Whh1, const float* __restrict__ Wout,
                     const float* __restrict__ bout, float* __restrict__ out)
{
    const int wg = blockIdx.x;
    const int bg = wg >> 4;
    const int j  = wg & 15;
    const int tid  = threadIdx.x;
    const int wave = tid >> 6;
    const int q  = (tid >> 4) & 3;
    const int ln = tid & 15;
    const int mycol = j * 16 + wave * 4 + q;
    const int myb   = bg * 16 + ln;

    __shared__ u32 hs0[2][16 * 132];           // parity planes, row-major packed pairs
    __shared__ u32 hs1[2][16 * 132];

    // ---- A-frags: packed-gate weight rows (m = c*4 + g) ----
    bf16x8 wf[3][8];
    {
        const float* mats[3] = { Whh0, Wih1, Whh1 };
        const int arow = (ln & 3) * H + j * 16 + wave * 4 + (ln >> 2);
        #pragma unroll
        for (int mm = 0; mm < 3; mm++) {
            const float* s = mats[mm] + arow * H;
            #pragma unroll
            for (int kk = 0; kk < 8; kk++) wf[mm][kk] = pack8(s + kk * 32 + q * 8);
        }
    }
    const bool doOut = (j < 4) && (wave == 0);
    bf16x8 wo[8];
    float bor[4] = {0.f, 0.f, 0.f, 0.f};
    if (doOut) {
        const int orow = j * 16 + ln;          // natural rows: C m = out-col
        const float* s = Wout + orow * H;
        #pragma unroll
        for (int kk = 0; kk < 8; kk++) wo[kk] = pack8(s + kk * 32 + q * 8);
        #pragma unroll
        for (int r = 0; r < 4; r++) bor[r] = bout[j * 16 + q * 4 + r];
    }

    // ---- per-lane gate biases + cell state ----
    float gxr0[4], gxr1[4];
    #pragma unroll
    for (int r = 0; r < 4; r++) {
        u32 v = gxb0u[myb * 512 + ((r * 256 + mycol) >> 1)];
        gxr0[r] = bs2f((unsigned short)((mycol & 1) ? (v >> 16) : (v & 0xFFFFu)));
        gxr1[r] = gxb1[r * 256 + mycol];
    }
    float creg0 = c0g[myb * H + mycol];
    float creg1 = c1g[myb * H + mycol];

    u64* A0 = h0B0 + bg * 2048;   // cluster slices: 16 rows x 128 pair-slots
    u64* A1 = h0B1 + bg * 2048;
    u64* B0 = h1B0 + bg * 2048;
    u64* B1 = h1B1 + bg * 2048;

    const int pubslot = ln * 128 + j * 8 + wave * 2 + (q >> 1);   // even-q lanes
    const bool pubLane = ((q & 1) == 0);

    // ---- carried h0 poll registers; preloop: k=0 snapshot from A1 (tag 0) ----
    u64 v0[8];
    #pragma unroll
    for (int i = 0; i < 8; i++) v0[i] = sys_load_u64(A1 + i * 256 + tid);

    for (int k = 0; k <= SEQ + 1; k++) {
        const u64* P1 = (k & 1) ? B1 : B0;  u64* C1 = (k & 1) ? B0 : B1;
        u64* C0 = (k & 1) ? A1 : A0;
        const int par = k & 1;

        // ---- issue h1 tag-k loads FIRST (least slack; latency overlaps h0) ----
        u64 v1[8];
        if (k >= 1) {
            #pragma unroll
            for (int i = 0; i < 8; i++) v1[i] = sys_load_u64(P1 + i * 256 + tid);
        }

        // ---- h0 staging: carried snapshot check, reload-all fallback ----
        if (k <= SEQ) {
            const u64* P0 = (k & 1) ? A0 : A1;
            bool ok = true;
            #pragma unroll
            for (int i = 0; i < 8; i++) ok = ok && ((u32)(v0[i] >> 32) == (u32)k);
            int guard = 0;
            while (!ok && guard < 16384) {
                ok = true;
                #pragma unroll
                for (int i = 0; i < 8; i++) v0[i] = sys_load_u64(P0 + i * 256 + tid);
                #pragma unroll
                for (int i = 0; i < 8; i++) ok = ok && ((u32)(v0[i] >> 32) == (u32)k);
                guard++;
            }
            u32* dst = hs0[par];
            #pragma unroll
            for (int i = 0; i < 8; i++) { int s = i * 256 + tid; dst[(s >> 7) * 132 + (s & 127)] = (u32)v0[i]; }
        }

        // ---- h1 staging: check issued loads, reload-all until tag k ----
        if (k >= 1) {
            bool ok = true;
            #pragma unroll
            for (int i = 0; i < 8; i++) ok = ok && ((u32)(v1[i] >> 32) == (u32)k);
            int guard = 0;
            while (!ok && guard < 16384) {
                ok = true;
                #pragma unroll
                for (int i = 0; i < 8; i++) v1[i] = sys_load_u64(P1 + i * 256 + tid);
                #pragma unroll
                for (int i = 0; i < 8; i++) ok = ok && ((u32)(v1[i] >> 32) == (u32)k);
                guard++;
            }
            u32* dst = hs1[par];
            #pragma unroll
            for (int i = 0; i < 8; i++) { int s = i * 256 + tid; dst[(s >> 7) * 132 + (s & 127)] = (u32)v1[i]; }
        }
        __syncthreads();                       // single barrier per iteration

        // ---- h0 B-frags (batch row ln) ----
        bf16x8 hb0[8];
        {
            const unsigned short* b0p = (const unsigned short*)hs0[par];
            #pragma unroll
            for (int kk = 0; kk < 8; kk++)
                hb0[kk] = *(const bf16x8*)(b0p + ln * 264 + kk * 32 + q * 8);
        }
        // ---- h1 B-frags ----
        bf16x8 hb1[8];
        {
            const unsigned short* b1p = (const unsigned short*)hs1[par];
            #pragma unroll
            for (int kk = 0; kk < 8; kk++)
                hb1[kk] = *(const bf16x8*)(b1p + ln * 264 + kk * 32 + q * 8);
        }

        // ---- layer 0, step k: gates in acc, publish from regs ----
        if (k < SEQ) {
            f32x4 acc = {0.f, 0.f, 0.f, 0.f};
            #pragma unroll
            for (int kk = 0; kk < 8; kk++)
                acc = __builtin_amdgcn_mfma_f32_16x16x32_bf16(wf[0][kk], hb0[kk], acc, 0, 0, 0);
            float i_ = sigm(acc[0] + gxr0[0]);
            float f_ = sigm(acc[1] + gxr0[1]);
            float g_ = tanhf_(acc[2] + gxr0[2]);
            float o_ = sigm(acc[3] + gxr0[3]);
            creg0 = f_ * creg0 + i_ * g_;
            int us = (int)(u32)(unsigned short)f2bs(o_ * tanhf_(creg0));
            int other = __shfl_xor(us, 16);    // q <-> q^1 (col pair partner)
            if (pubLane) {
                u32 pa = (u32)us | ((u32)other << 16);
                sys_store_u64(C0 + pubslot, ((u64)(u32)(k + 1) << 32) | (u64)pa);
            }
        }

        // ---- layer 1, step k-1 ----
        if (k >= 1 && k <= SEQ) {
            f32x4 acc = {0.f, 0.f, 0.f, 0.f};
            #pragma unroll
            for (int kk = 0; kk < 8; kk++)
                acc = __builtin_amdgcn_mfma_f32_16x16x32_bf16(wf[1][kk], hb0[kk], acc, 0, 0, 0);
            #pragma unroll
            for (int kk = 0; kk < 8; kk++)
                acc = __builtin_amdgcn_mfma_f32_16x16x32_bf16(wf[2][kk], hb1[kk], acc, 0, 0, 0);
            float i_ = sigm(acc[0] + gxr1[0]);
            float f_ = sigm(acc[1] + gxr1[1]);
            float g_ = tanhf_(acc[2] + gxr1[2]);
            float o_ = sigm(acc[3] + gxr1[3]);
            creg1 = f_ * creg1 + i_ * g_;
            int us = (int)(u32)(unsigned short)f2bs(o_ * tanhf_(creg1));
            int other = __shfl_xor(us, 16);
            if (pubLane) {
                u32 pa = (u32)us | ((u32)other << 16);
                sys_store_u64(C1 + pubslot, ((u64)(u32)(k + 1) << 32) | (u64)pa);
            }
        }

        // ---- LATE h0 prefetch for k+1: all wgs' h0 publishes (issued ~0.4T
        //      of this iter) are visible by now -> carried check at top of k+1
        //      almost always hits with zero fresh loads. Out-proj + loop
        //      overhead cover part of the load latency. Stale lines hold tag
        //      k-1 (C0(k) = P0(k-1)): no false accept.
        if (k < SEQ) {
            #pragma unroll
            for (int i = 0; i < 8; i++) v0[i] = sys_load_u64(C0 + i * 256 + tid);
        }

        // ---- output projection, step k-2 (reuses hb1 = h1_{k-2}); f32x4 store ----
        if (k >= 2 && doOut) {
            f32x4 acc = {0.f, 0.f, 0.f, 0.f};
            #pragma unroll
            for (int kk = 0; kk < 8; kk++)
                acc = __builtin_amdgcn_mfma_f32_16x16x32_bf16(wo[kk], hb1[kk], acc, 0, 0, 0);
            f32x4 res;
            #pragma unroll
            for (int r = 0; r < 4; r++) res[r] = acc[r] + bor[r];
            *(f32x4*)&out[(bg * 16 + ln) * (SEQ * OUTD) + (k - 2) * OUTD + j * 16 + q * 4] = res;
        }
    }
}

extern "C" void kernel_launch(void* const* d_in, const int* in_sizes, int n_in,
                              void* d_out, int out_size, void* d_ws, size_t ws_size,
                              hipStream_t stream) {
    const float* z     = (const float*)d_in[0];
    const float* Whid  = (const float*)d_in[1];
    const float* bhid  = (const float*)d_in[2];
    const float* Wcell = (const float*)d_in[3];
    const float* bcell = (const float*)d_in[4];
    const float* Win   = (const float*)d_in[5];
    const float* bin   = (const float*)d_in[6];
    const float* Wih0  = (const float*)d_in[7];
    const float* Whh0  = (const float*)d_in[8];
    const float* bih0  = (const float*)d_in[9];
    const float* bhh0  = (const float*)d_in[10];
    const float* Wih1  = (const float*)d_in[11];
    const float* Whh1  = (const float*)d_in[12];
    const float* bih1  = (const float*)d_in[13];
    const float* bhh1  = (const float*)d_in[14];
    const float* Wout  = (const float*)d_in[15];
    const float* bout  = (const float*)d_in[16];
    float* out = (float*)d_out;

    // workspace: 2,101,248 B total (== round-8-proven size)
    u32*   gxb0u = (u32*)d_ws;                   // [131072] bf16-pair gate biases
    float* gxb1  = (float*)(gxb0u + 131072);     // [1024]
    float* c0    = gxb1 + 1024;                  // [65536]
    float* c1    = c0 + 65536;                   // [65536]
    u64*   h0B0  = (u64*)(c1 + 65536);           // [32768] tagged pair-slots x4
    u64*   h0B1  = h0B0 + 32768;
    u64*   h1B0  = h0B1 + 32768;
    u64*   h1B1  = h1B0 + 32768;

    lstm_prologue_init<<<772, 256, 0, stream>>>(z, Whid, bhid, Wcell, bcell,
                                                bih1, bhh1, h0B1, h1B1, c0, c1, gxb1);
    lstm_prologue_gx0<<<dim3(2, 256), 256, 0, stream>>>(z, Win, bin, Wih0, bih0, bhh0, gxb0u);

    void* kargs[] = { (void*)&gxb0u, (void*)&gxb1, (void*)&c0, (void*)&c1,
                      (void*)&h0B0, (void*)&h0B1, (void*)&h1B0, (void*)&h1B1,
                      (void*)&Whh0, (void*)&Wih1, (void*)&Whh1, (void*)&Wout,
                      (void*)&bout, (void*)&out };
    hipError_t ce = hipLaunchCooperativeKernel((const void*)lstm_persistent,
                                               dim3(256), dim3(256), kargs, 0, stream);
    if (ce != hipSuccess) {
        lstm_persistent<<<256, 256, 0, stream>>>(gxb0u, gxb1, c0, c1,
                                                 h0B0, h0B1, h1B0, h1B1,
                                                 Whh0, Wih1, Whh1, Wout, bout, out);
    }
}

// Round 4
// 1507.287 us; speedup vs baseline: 1.2280x; 1.2280x over previous
//
#include <hip/hip_runtime.h>
#include <hip/hip_bf16.h>

#define LAT 128
#define H 256
#define OUTD 64
#define SEQ 512

typedef short bf16x8 __attribute__((ext_vector_type(8)));
typedef float f32x4  __attribute__((ext_vector_type(4)));
typedef unsigned long long u64;
typedef unsigned u32;

__device__ __forceinline__ float sigm(float x)  { return 1.f / (1.f + __expf(-x)); }
__device__ __forceinline__ float tanhf_(float x){ return 1.f - 2.f / (__expf(2.f * x) + 1.f); }

__device__ __forceinline__ short f2bs(float x) {
    __hip_bfloat16 b = __float2bfloat16(x);
    return *reinterpret_cast<short*>(&b);
}
__device__ __forceinline__ float bs2f(unsigned short h) {
    u32 b = ((u32)h) << 16;
    float f; __builtin_memcpy(&f, &b, 4); return f;
}
__device__ __forceinline__ u32 f2pair(float a, float b) {
    return ((u32)(unsigned short)f2bs(b) << 16) | (u32)(unsigned short)f2bs(a);
}
__device__ __forceinline__ bf16x8 pack8(const float* s) {
    bf16x8 v;
    v[0]=f2bs(s[0]); v[1]=f2bs(s[1]); v[2]=f2bs(s[2]); v[3]=f2bs(s[3]);
    v[4]=f2bs(s[4]); v[5]=f2bs(s[5]); v[6]=f2bs(s[6]); v[7]=f2bs(s[7]);
    return v;
}

// ---- Transport: SYSTEM scope, R0-proven protocol. This round changes ONLY
// the issue-order of poll loads vs publish stores. vmcnt retires in issue
// order and loads/stores share it: a publish store issued BEFORE poll loads
// forces every poll check (and barrier vmcnt(0)) to wait the store's
// system-scope ack (~1000cy). Issuing poll loads FIRST makes the check's
// counted vmcnt retire only the loads; the store ack drains off-path.
__device__ __forceinline__ u64 sys_load_u64(const u64* p) {
    return __hip_atomic_load((u64*)p, __ATOMIC_RELAXED, __HIP_MEMORY_SCOPE_SYSTEM);
}
__device__ __forceinline__ void sys_store_u64(u64* p, u64 v) {
    __hip_atomic_store(p, v, __ATOMIC_RELAXED, __HIP_MEMORY_SCOPE_SYSTEM);
}

// ---------------- Prologue 1 (round-8 verbatim): tagged h-init, c-init, L1 bias ----
__global__ void lstm_prologue_init(const float* __restrict__ z,
                                   const float* __restrict__ Whid,
                                   const float* __restrict__ bhid,
                                   const float* __restrict__ Wcell,
                                   const float* __restrict__ bcell,
                                   const float* __restrict__ bih1,
                                   const float* __restrict__ bhh1,
                                   u64* __restrict__ h0B1,
                                   u64* __restrict__ h1B1,
                                   float* __restrict__ c0,
                                   float* __restrict__ c1,
                                   float* __restrict__ gxb1)
{
    int t = blockIdx.x * 256 + threadIdx.x;
    if (t < 65536) {                     // tagged hidden-init: 2 layers x 256 b x 128 pairs
        int layer = t >> 15;
        int tt = t & 32767;
        int b = tt >> 7, cp = tt & 127;
        int colA = layer * H + 2 * cp;
        const float* zr = z + b * LAT;
        const float* wA = Whid + colA * LAT;
        const float* wB = wA + LAT;
        float a0 = bhid[colA], a1 = bhid[colA + 1];
        for (int k = 0; k < LAT; k++) { float zv = zr[k]; a0 += zv * wA[k]; a1 += zv * wB[k]; }
        u64 v = ((u64)(u32)layer << 32) | (u64)f2pair(a0, a1);
        (layer ? h1B1 : h0B1)[b * 128 + cp] = v;
    } else if (t < 196608) {             // cell init: [256 x 512]
        int tt = t - 65536;
        int b = tt >> 9, col = tt & 511;
        const float* w  = Wcell + col * LAT;
        const float* zr = z + b * LAT;
        float acc = bcell[col];
        for (int k = 0; k < LAT; k++) acc += zr[k] * w[k];
        if (col < H) c0[b * H + col] = acc;
        else         c1[b * H + (col - H)] = acc;
    } else if (t < 197632) {             // layer-1 gate bias vector [1024]
        int g = t - 196608;
        gxb1[g] = bih1[g] + bhh1[g];
    }
}

// ---------------- Prologue 2 (round-8 verbatim): gx0 packed bf16 pairs ----
__global__ void lstm_prologue_gx0(const float* __restrict__ z,
                                  const float* __restrict__ Win,
                                  const float* __restrict__ bin,
                                  const float* __restrict__ Wih0,
                                  const float* __restrict__ bih0,
                                  const float* __restrict__ bhh0,
                                  u32* __restrict__ gxb0u)
{
    __shared__ float xs[H];
    const int b = blockIdx.y;
    const int tid = threadIdx.x;
    {
        const float* w  = Win + tid * LAT;
        const float* zr = z + b * LAT;
        float acc = bin[tid];
        for (int k = 0; k < LAT; k++) acc += zr[k] * w[k];
        xs[tid] = acc;
    }
    __syncthreads();
    const int cA = blockIdx.x * 512 + 2 * tid;
    const float* wA = Wih0 + cA * H;
    const float* wB = wA + H;
    float a0 = bih0[cA]     + bhh0[cA];
    float a1 = bih0[cA + 1] + bhh0[cA + 1];
    for (int k = 0; k < H; k++) { float xv = xs[k]; a0 += xv * wA[k]; a1 += xv * wB[k]; }
    gxb0u[b * 512 + blockIdx.x * 256 + tid] = f2pair(a0, a1);
}

// ---------------- Persistent kernel ----------------
// 256 wgs x 256 thr. Cluster bg = wg>>4, wg j = wg&15 owns 16 hidden cols.
// R0 STRUCTURE (two barriers, R0 poll positions, snapshot spins) with
// vmcnt-decoupled scheduling:
//  - h1 poll loads issued right after B1 (slack 0.7T: h1 tag k published at
//    ~0.85T of iter k-1), BEFORE the L0 publish store; latency hides under
//    L0 MFMA+nonlin; checked after L0 publish with counted vmcnt (loads are
//    older than the store -> store ack excluded).
//  - h0 tag-(k+1) loads prefetched late in iter k (~0.8T; published at ~0.4T
//    by all wgs -> 0.4T slack, the validated part of R3), BEFORE the L1
//    publish store; carried in regs; top-of-iteration check is register-only.
//  - sched_barrier(0) pins load-issue before the publish stores.
// Parity-plane safety identical to R0 (stage(k+1) writes plane par^1 only
// after B1/B2 of k+1 > all reads of plane par^1 at iter k).
__global__ __launch_bounds__(256, 1)
void lstm_persistent(const u32* __restrict__ gxb0u, const float* __restrict__ gxb1,
                     const float* __restrict__ c0g, const float* __restrict__ c1g,
                     u64* __restrict__ h0B0, u64* __restrict__ h0B1,
                     u64* __restrict__ h1B0, u64* __restrict__ h1B1,
                     const float* __restrict__ Whh0, const float* __restrict__ Wih1,
                     const float* __restrict__ Whh1, const float* __restrict__ Wout,
                     const float* __restrict__ bout, float* __restrict__ out)
{
    const int wg = blockIdx.x;
    const int bg = wg >> 4;
    const int j  = wg & 15;
    const int tid  = threadIdx.x;
    const int wave = tid >> 6;
    const int q  = (tid >> 4) & 3;
    const int ln = tid & 15;
    const int mycol = j * 16 + wave * 4 + q;
    const int myb   = bg * 16 + ln;

    __shared__ u32 hs0[2][16 * 132];           // parity planes, row-major packed pairs
    __shared__ u32 hs1[2][16 * 132];

    // ---- A-frags: packed-gate weight rows (m = c*4 + g) ----
    bf16x8 wf[3][8];
    {
        const float* mats[3] = { Whh0, Wih1, Whh1 };
        const int arow = (ln & 3) * H + j * 16 + wave * 4 + (ln >> 2);
        #pragma unroll
        for (int mm = 0; mm < 3; mm++) {
            const float* s = mats[mm] + arow * H;
            #pragma unroll
            for (int kk = 0; kk < 8; kk++) wf[mm][kk] = pack8(s + kk * 32 + q * 8);
        }
    }
    const bool doOut = (j < 4) && (wave == 0);
    bf16x8 wo[8];
    float bor[4] = {0.f, 0.f, 0.f, 0.f};
    if (doOut) {
        const int orow = j * 16 + ln;          // natural rows: C m = out-col
        const float* s = Wout + orow * H;
        #pragma unroll
        for (int kk = 0; kk < 8; kk++) wo[kk] = pack8(s + kk * 32 + q * 8);
        #pragma unroll
        for (int r = 0; r < 4; r++) bor[r] = bout[j * 16 + q * 4 + r];
    }

    // ---- per-lane gate biases + cell state ----
    float gxr0[4], gxr1[4];
    #pragma unroll
    for (int r = 0; r < 4; r++) {
        u32 v = gxb0u[myb * 512 + ((r * 256 + mycol) >> 1)];
        gxr0[r] = bs2f((unsigned short)((mycol & 1) ? (v >> 16) : (v & 0xFFFFu)));
        gxr1[r] = gxb1[r * 256 + mycol];
    }
    float creg0 = c0g[myb * H + mycol];
    float creg1 = c1g[myb * H + mycol];

    u64* A0 = h0B0 + bg * 2048;   // cluster slices: 16 rows x 128 pair-slots
    u64* A1 = h0B1 + bg * 2048;
    u64* B0 = h1B0 + bg * 2048;
    u64* B1 = h1B1 + bg * 2048;

    const int pubslot = ln * 128 + j * 8 + wave * 2 + (q >> 1);   // even-q lanes
    const bool pubLane = ((q & 1) == 0);

    // ---- carried h0 poll regs; preloop: k=0 snapshot from A1 (prologue tag 0) ----
    u64 v0[8];
    #pragma unroll
    for (int i = 0; i < 8; i++) v0[i] = sys_load_u64(A1 + i * 256 + tid);

    for (int k = 0; k <= SEQ + 1; k++) {
        const u64* P1 = (k & 1) ? B1 : B0;  u64* C1 = (k & 1) ? B0 : B1;
        u64* C0 = (k & 1) ? A1 : A0;
        const int par = k & 1;

        // ---- TOP staging: h0 (carried snapshot check; reload-all fallback) ----
        if (k <= SEQ) {
            const u64* P0 = (k & 1) ? A0 : A1;
            bool ok = true;
            #pragma unroll
            for (int i = 0; i < 8; i++) ok = ok && ((u32)(v0[i] >> 32) == (u32)k);
            int guard = 0;
            while (!ok && guard < 16384) {
                ok = true;
                #pragma unroll
                for (int i = 0; i < 8; i++) v0[i] = sys_load_u64(P0 + i * 256 + tid);
                #pragma unroll
                for (int i = 0; i < 8; i++) ok = ok && ((u32)(v0[i] >> 32) == (u32)k);
                guard++;
            }
            u32* dst = hs0[par];
            #pragma unroll
            for (int i = 0; i < 8; i++) { int s = i * 256 + tid; dst[(s >> 7) * 132 + (s & 127)] = (u32)v0[i]; }
        }
        __syncthreads();                       // B1

        // ---- h0 B-frags (batch row ln) ----
        bf16x8 hb0[8];
        {
            const unsigned short* b0p = (const unsigned short*)hs0[par];
            #pragma unroll
            for (int kk = 0; kk < 8; kk++)
                hb0[kk] = *(const bf16x8*)(b0p + ln * 264 + kk * 32 + q * 8);
        }

        // ---- issue h1 tag-k poll loads NOW (0.7T slack; hide under L0;
        //      older than the L0 publish store -> check excludes store ack) ----
        u64 v1[8];
        if (k >= 1) {
            #pragma unroll
            for (int i = 0; i < 8; i++) v1[i] = sys_load_u64(P1 + i * 256 + tid);
        }
        __builtin_amdgcn_sched_barrier(0);     // pin: loads issued before L0 block

        // ---- layer 0, step k: gates in acc, publish from regs ----
        if (k < SEQ) {
            f32x4 acc = {0.f, 0.f, 0.f, 0.f};
            #pragma unroll
            for (int kk = 0; kk < 8; kk++)
                acc = __builtin_amdgcn_mfma_f32_16x16x32_bf16(wf[0][kk], hb0[kk], acc, 0, 0, 0);
            float i_ = sigm(acc[0] + gxr0[0]);
            float f_ = sigm(acc[1] + gxr0[1]);
            float g_ = tanhf_(acc[2] + gxr0[2]);
            float o_ = sigm(acc[3] + gxr0[3]);
            creg0 = f_ * creg0 + i_ * g_;
            int us = (int)(u32)(unsigned short)f2bs(o_ * tanhf_(creg0));
            int other = __shfl_xor(us, 16);    // q <-> q^1 (col pair partner)
            if (pubLane) {
                u32 pa = (u32)us | ((u32)other << 16);
                sys_store_u64(C0 + pubslot, ((u64)(u32)(k + 1) << 32) | (u64)pa);
            }
        }

        // ---- MID staging: h1 (check prefetched snapshot; reload-all fallback) ----
        if (k >= 1) {
            bool ok = true;
            #pragma unroll
            for (int i = 0; i < 8; i++) ok = ok && ((u32)(v1[i] >> 32) == (u32)k);
            int guard = 0;
            while (!ok && guard < 16384) {
                ok = true;
                #pragma unroll
                for (int i = 0; i < 8; i++) v1[i] = sys_load_u64(P1 + i * 256 + tid);
                #pragma unroll
                for (int i = 0; i < 8; i++) ok = ok && ((u32)(v1[i] >> 32) == (u32)k);
                guard++;
            }
            u32* dst = hs1[par];
            #pragma unroll
            for (int i = 0; i < 8; i++) { int s = i * 256 + tid; dst[(s >> 7) * 132 + (s & 127)] = (u32)v1[i]; }
        }
        __syncthreads();                       // B2

        // ---- h1 B-frags ----
        bf16x8 hb1[8];
        {
            const unsigned short* b1p = (const unsigned short*)hs1[par];
            #pragma unroll
            for (int kk = 0; kk < 8; kk++)
                hb1[kk] = *(const bf16x8*)(b1p + ln * 264 + kk * 32 + q * 8);
        }

        // ---- layer 1, step k-1: compute gates (publish deferred below) ----
        u32 pa1 = 0; bool pub1 = false;
        if (k >= 1 && k <= SEQ) {
            f32x4 acc = {0.f, 0.f, 0.f, 0.f};
            #pragma unroll
            for (int kk = 0; kk < 8; kk++)
                acc = __builtin_amdgcn_mfma_f32_16x16x32_bf16(wf[1][kk], hb0[kk], acc, 0, 0, 0);
            #pragma unroll
            for (int kk = 0; kk < 8; kk++)
                acc = __builtin_amdgcn_mfma_f32_16x16x32_bf16(wf[2][kk], hb1[kk], acc, 0, 0, 0);
            float i_ = sigm(acc[0] + gxr1[0]);
            float f_ = sigm(acc[1] + gxr1[1]);
            float g_ = tanhf_(acc[2] + gxr1[2]);
            float o_ = sigm(acc[3] + gxr1[3]);
            creg1 = f_ * creg1 + i_ * g_;
            int us = (int)(u32)(unsigned short)f2bs(o_ * tanhf_(creg1));
            int other = __shfl_xor(us, 16);
            pa1 = (u32)us | ((u32)other << 16);
            pub1 = pubLane;
        }

        // ---- LATE h0 prefetch for k+1 (published at ~0.4T this iter by all
        //      wgs -> 0.4T slack). Issued BEFORE the L1 publish store so the
        //      top-of-(k+1) check's counted vmcnt excludes the store ack. ----
        if (k < SEQ) {
            #pragma unroll
            for (int i = 0; i < 8; i++) v0[i] = sys_load_u64(C0 + i * 256 + tid);
        }
        __builtin_amdgcn_sched_barrier(0);     // pin: prefetch before publish store

        // ---- layer-1 publish (store younger than all poll loads) ----
        if (pub1) {
            sys_store_u64(C1 + pubslot, ((u64)(u32)(k + 1) << 32) | (u64)pa1);
        }

        // ---- output projection, step k-2 (reuses hb1 = h1_{k-2}); f32x4 store ----
        if (k >= 2 && doOut) {
            f32x4 acc = {0.f, 0.f, 0.f, 0.f};
            #pragma unroll
            for (int kk = 0; kk < 8; kk++)
                acc = __builtin_amdgcn_mfma_f32_16x16x32_bf16(wo[kk], hb1[kk], acc, 0, 0, 0);
            f32x4 res;
            #pragma unroll
            for (int r = 0; r < 4; r++) res[r] = acc[r] + bor[r];
            *(f32x4*)&out[(bg * 16 + ln) * (SEQ * OUTD) + (k - 2) * OUTD + j * 16 + q * 4] = res;
        }
    }
}

extern "C" void kernel_launch(void* const* d_in, const int* in_sizes, int n_in,
                              void* d_out, int out_size, void* d_ws, size_t ws_size,
                              hipStream_t stream) {
    const float* z     = (const float*)d_in[0];
    const float* Whid  = (const float*)d_in[1];
    const float* bhid  = (const float*)d_in[2];
    const float* Wcell = (const float*)d_in[3];
    const float* bcell = (const float*)d_in[4];
    const float* Win   = (const float*)d_in[5];
    const float* bin   = (const float*)d_in[6];
    const float* Wih0  = (const float*)d_in[7];
    const float* Whh0  = (const float*)d_in[8];
    const float* bih0  = (const float*)d_in[9];
    const float* bhh0  = (const float*)d_in[10];
    const float* Wih1  = (const float*)d_in[11];
    const float* Whh1  = (const float*)d_in[12];
    const float* bih1  = (const float*)d_in[13];
    const float* bhh1  = (const float*)d_in[14];
    const float* Wout  = (const float*)d_in[15];
    const float* bout  = (const float*)d_in[16];
    float* out = (float*)d_out;

    // workspace: 2,101,248 B total (== round-8-proven size)
    u32*   gxb0u = (u32*)d_ws;                   // [131072] bf16-pair gate biases
    float* gxb1  = (float*)(gxb0u + 131072);     // [1024]
    float* c0    = gxb1 + 1024;                  // [65536]
    float* c1    = c0 + 65536;                   // [65536]
    u64*   h0B0  = (u64*)(c1 + 65536);           // [32768] tagged pair-slots x4
    u64*   h0B1  = h0B0 + 32768;
    u64*   h1B0  = h0B1 + 32768;
    u64*   h1B1  = h1B0 + 32768;

    lstm_prologue_init<<<772, 256, 0, stream>>>(z, Whid, bhid, Wcell, bcell,
                                                bih1, bhh1, h0B1, h1B1, c0, c1, gxb1);
    lstm_prologue_gx0<<<dim3(2, 256), 256, 0, stream>>>(z, Win, bin, Wih0, bih0, bhh0, gxb0u);

    void* kargs[] = { (void*)&gxb0u, (void*)&gxb1, (void*)&c0, (void*)&c1,
                      (void*)&h0B0, (void*)&h0B1, (void*)&h1B0, (void*)&h1B1,
                      (void*)&Whh0, (void*)&Wih1, (void*)&Whh1, (void*)&Wout,
                      (void*)&bout, (void*)&out };
    hipError_t ce = hipLaunchCooperativeKernel((const void*)lstm_persistent,
                                               dim3(256), dim3(256), kargs, 0, stream);
    if (ce != hipSuccess) {
        lstm_persistent<<<256, 256, 0, stream>>>(gxb0u, gxb1, c0, c1,
                                                 h0B0, h0B1, h1B0, h1B1,
                                                 Whh0, Wih1, Whh1, Wout, bout, out);
    }
}

// Round 5
// 1497.179 us; speedup vs baseline: 1.2363x; 1.0068x over previous
//
#include <hip/hip_runtime.h>
#include <hip/hip_bf16.h>

#define LAT 128
#define H 256
#define OUTD 64
#define SEQ 512

typedef short bf16x8 __attribute__((ext_vector_type(8)));
typedef float f32x4  __attribute__((ext_vector_type(4)));
typedef unsigned long long u64;
typedef unsigned u32;

__device__ __forceinline__ float sigm(float x)  { return 1.f / (1.f + __expf(-x)); }
__device__ __forceinline__ float tanhf_(float x){ return 1.f - 2.f / (__expf(2.f * x) + 1.f); }

__device__ __forceinline__ short f2bs(float x) {
    __hip_bfloat16 b = __float2bfloat16(x);
    return *reinterpret_cast<short*>(&b);
}
__device__ __forceinline__ float bs2f(unsigned short h) {
    u32 b = ((u32)h) << 16;
    float f; __builtin_memcpy(&f, &b, 4); return f;
}
__device__ __forceinline__ u32 f2pair(float a, float b) {
    return ((u32)(unsigned short)f2bs(b) << 16) | (u32)(unsigned short)f2bs(a);
}
__device__ __forceinline__ bf16x8 pack8(const float* s) {
    bf16x8 v;
    v[0]=f2bs(s[0]); v[1]=f2bs(s[1]); v[2]=f2bs(s[2]); v[3]=f2bs(s[3]);
    v[4]=f2bs(s[4]); v[5]=f2bs(s[5]); v[6]=f2bs(s[6]); v[7]=f2bs(s[7]);
    return v;
}

// ---- Transport: AGENT scope (single-variable change vs R4).
// Evidence: R2's agent build collapsed FETCH_SIZE 6.5x (transport becomes
// MALL-resident; system-scope polls are partially DRAM-served) but was
// confounded with regressive spin machinery. Agent scope = device coherence
// point (MALL), sufficient for cross-XCD persistent-kernel communication.
// Everything else (R4 structure, poll positions, reload-all snapshots,
// load-before-store scheduling) is byte-identical to the R4 base.
__device__ __forceinline__ u64 sys_load_u64(const u64* p) {
    return __hip_atomic_load((u64*)p, __ATOMIC_RELAXED, __HIP_MEMORY_SCOPE_AGENT);
}
__device__ __forceinline__ void sys_store_u64(u64* p, u64 v) {
    __hip_atomic_store(p, v, __ATOMIC_RELAXED, __HIP_MEMORY_SCOPE_AGENT);
}

// ---------------- Prologue 1 (round-8 verbatim): tagged h-init, c-init, L1 bias ----
__global__ void lstm_prologue_init(const float* __restrict__ z,
                                   const float* __restrict__ Whid,
                                   const float* __restrict__ bhid,
                                   const float* __restrict__ Wcell,
                                   const float* __restrict__ bcell,
                                   const float* __restrict__ bih1,
                                   const float* __restrict__ bhh1,
                                   u64* __restrict__ h0B1,
                                   u64* __restrict__ h1B1,
                                   float* __restrict__ c0,
                                   float* __restrict__ c1,
                                   float* __restrict__ gxb1)
{
    int t = blockIdx.x * 256 + threadIdx.x;
    if (t < 65536) {                     // tagged hidden-init: 2 layers x 256 b x 128 pairs
        int layer = t >> 15;
        int tt = t & 32767;
        int b = tt >> 7, cp = tt & 127;
        int colA = layer * H + 2 * cp;
        const float* zr = z + b * LAT;
        const float* wA = Whid + colA * LAT;
        const float* wB = wA + LAT;
        float a0 = bhid[colA], a1 = bhid[colA + 1];
        for (int k = 0; k < LAT; k++) { float zv = zr[k]; a0 += zv * wA[k]; a1 += zv * wB[k]; }
        u64 v = ((u64)(u32)layer << 32) | (u64)f2pair(a0, a1);
        (layer ? h1B1 : h0B1)[b * 128 + cp] = v;
    } else if (t < 196608) {             // cell init: [256 x 512]
        int tt = t - 65536;
        int b = tt >> 9, col = tt & 511;
        const float* w  = Wcell + col * LAT;
        const float* zr = z + b * LAT;
        float acc = bcell[col];
        for (int k = 0; k < LAT; k++) acc += zr[k] * w[k];
        if (col < H) c0[b * H + col] = acc;
        else         c1[b * H + (col - H)] = acc;
    } else if (t < 197632) {             // layer-1 gate bias vector [1024]
        int g = t - 196608;
        gxb1[g] = bih1[g] + bhh1[g];
    }
}

// ---------------- Prologue 2 (round-8 verbatim): gx0 packed bf16 pairs ----
__global__ void lstm_prologue_gx0(const float* __restrict__ z,
                                  const float* __restrict__ Win,
                                  const float* __restrict__ bin,
                                  const float* __restrict__ Wih0,
                                  const float* __restrict__ bih0,
                                  const float* __restrict__ bhh0,
                                  u32* __restrict__ gxb0u)
{
    __shared__ float xs[H];
    const int b = blockIdx.y;
    const int tid = threadIdx.x;
    {
        const float* w  = Win + tid * LAT;
        const float* zr = z + b * LAT;
        float acc = bin[tid];
        for (int k = 0; k < LAT; k++) acc += zr[k] * w[k];
        xs[tid] = acc;
    }
    __syncthreads();
    const int cA = blockIdx.x * 512 + 2 * tid;
    const float* wA = Wih0 + cA * H;
    const float* wB = wA + H;
    float a0 = bih0[cA]     + bhh0[cA];
    float a1 = bih0[cA + 1] + bhh0[cA + 1];
    for (int k = 0; k < H; k++) { float xv = xs[k]; a0 += xv * wA[k]; a1 += xv * wB[k]; }
    gxb0u[b * 512 + blockIdx.x * 256 + tid] = f2pair(a0, a1);
}

// ---------------- Persistent kernel ----------------
// 256 wgs x 256 thr. Cluster bg = wg>>4, wg j = wg&15 owns 16 hidden cols.
// R4 STRUCTURE (two barriers, R0 poll positions, snapshot spins,
// vmcnt-decoupled load-before-store scheduling), AGENT-scope transport.
// Additional compute-local change: layer-1 uses TWO independent MFMA
// accumulators (Wih1*h0 and Whh1*h1) summed at the end -> dependent chain
// 16 -> 8+8 pipelined. Protocol untouched.
__global__ __launch_bounds__(256, 1)
void lstm_persistent(const u32* __restrict__ gxb0u, const float* __restrict__ gxb1,
                     const float* __restrict__ c0g, const float* __restrict__ c1g,
                     u64* __restrict__ h0B0, u64* __restrict__ h0B1,
                     u64* __restrict__ h1B0, u64* __restrict__ h1B1,
                     const float* __restrict__ Whh0, const float* __restrict__ Wih1,
                     const float* __restrict__ Whh1, const float* __restrict__ Wout,
                     const float* __restrict__ bout, float* __restrict__ out)
{
    const int wg = blockIdx.x;
    const int bg = wg >> 4;
    const int j  = wg & 15;
    const int tid  = threadIdx.x;
    const int wave = tid >> 6;
    const int q  = (tid >> 4) & 3;
    const int ln = tid & 15;
    const int mycol = j * 16 + wave * 4 + q;
    const int myb   = bg * 16 + ln;

    __shared__ u32 hs0[2][16 * 132];           // parity planes, row-major packed pairs
    __shared__ u32 hs1[2][16 * 132];

    // ---- A-frags: packed-gate weight rows (m = c*4 + g) ----
    bf16x8 wf[3][8];
    {
        const float* mats[3] = { Whh0, Wih1, Whh1 };
        const int arow = (ln & 3) * H + j * 16 + wave * 4 + (ln >> 2);
        #pragma unroll
        for (int mm = 0; mm < 3; mm++) {
            const float* s = mats[mm] + arow * H;
            #pragma unroll
            for (int kk = 0; kk < 8; kk++) wf[mm][kk] = pack8(s + kk * 32 + q * 8);
        }
    }
    const bool doOut = (j < 4) && (wave == 0);
    bf16x8 wo[8];
    float bor[4] = {0.f, 0.f, 0.f, 0.f};
    if (doOut) {
        const int orow = j * 16 + ln;          // natural rows: C m = out-col
        const float* s = Wout + orow * H;
        #pragma unroll
        for (int kk = 0; kk < 8; kk++) wo[kk] = pack8(s + kk * 32 + q * 8);
        #pragma unroll
        for (int r = 0; r < 4; r++) bor[r] = bout[j * 16 + q * 4 + r];
    }

    // ---- per-lane gate biases + cell state ----
    float gxr0[4], gxr1[4];
    #pragma unroll
    for (int r = 0; r < 4; r++) {
        u32 v = gxb0u[myb * 512 + ((r * 256 + mycol) >> 1)];
        gxr0[r] = bs2f((unsigned short)((mycol & 1) ? (v >> 16) : (v & 0xFFFFu)));
        gxr1[r] = gxb1[r * 256 + mycol];
    }
    float creg0 = c0g[myb * H + mycol];
    float creg1 = c1g[myb * H + mycol];

    u64* A0 = h0B0 + bg * 2048;   // cluster slices: 16 rows x 128 pair-slots
    u64* A1 = h0B1 + bg * 2048;
    u64* B0 = h1B0 + bg * 2048;
    u64* B1 = h1B1 + bg * 2048;

    const int pubslot = ln * 128 + j * 8 + wave * 2 + (q >> 1);   // even-q lanes
    const bool pubLane = ((q & 1) == 0);

    // ---- carried h0 poll regs; preloop: k=0 snapshot from A1 (prologue tag 0) ----
    u64 v0[8];
    #pragma unroll
    for (int i = 0; i < 8; i++) v0[i] = sys_load_u64(A1 + i * 256 + tid);

    for (int k = 0; k <= SEQ + 1; k++) {
        const u64* P1 = (k & 1) ? B1 : B0;  u64* C1 = (k & 1) ? B0 : B1;
        u64* C0 = (k & 1) ? A1 : A0;
        const int par = k & 1;

        // ---- TOP staging: h0 (carried snapshot check; reload-all fallback) ----
        if (k <= SEQ) {
            const u64* P0 = (k & 1) ? A0 : A1;
            bool ok = true;
            #pragma unroll
            for (int i = 0; i < 8; i++) ok = ok && ((u32)(v0[i] >> 32) == (u32)k);
            int guard = 0;
            while (!ok && guard < 16384) {
                ok = true;
                #pragma unroll
                for (int i = 0; i < 8; i++) v0[i] = sys_load_u64(P0 + i * 256 + tid);
                #pragma unroll
                for (int i = 0; i < 8; i++) ok = ok && ((u32)(v0[i] >> 32) == (u32)k);
                guard++;
            }
            u32* dst = hs0[par];
            #pragma unroll
            for (int i = 0; i < 8; i++) { int s = i * 256 + tid; dst[(s >> 7) * 132 + (s & 127)] = (u32)v0[i]; }
        }
        __syncthreads();                       // B1

        // ---- h0 B-frags (batch row ln) ----
        bf16x8 hb0[8];
        {
            const unsigned short* b0p = (const unsigned short*)hs0[par];
            #pragma unroll
            for (int kk = 0; kk < 8; kk++)
                hb0[kk] = *(const bf16x8*)(b0p + ln * 264 + kk * 32 + q * 8);
        }

        // ---- issue h1 tag-k poll loads NOW (0.7T slack; hide under L0;
        //      older than the L0 publish store -> check excludes store ack) ----
        u64 v1[8];
        if (k >= 1) {
            #pragma unroll
            for (int i = 0; i < 8; i++) v1[i] = sys_load_u64(P1 + i * 256 + tid);
        }
        __builtin_amdgcn_sched_barrier(0);     // pin: loads issued before L0 block

        // ---- layer 0, step k: gates in acc, publish from regs ----
        if (k < SEQ) {
            f32x4 acc = {0.f, 0.f, 0.f, 0.f};
            #pragma unroll
            for (int kk = 0; kk < 8; kk++)
                acc = __builtin_amdgcn_mfma_f32_16x16x32_bf16(wf[0][kk], hb0[kk], acc, 0, 0, 0);
            float i_ = sigm(acc[0] + gxr0[0]);
            float f_ = sigm(acc[1] + gxr0[1]);
            float g_ = tanhf_(acc[2] + gxr0[2]);
            float o_ = sigm(acc[3] + gxr0[3]);
            creg0 = f_ * creg0 + i_ * g_;
            int us = (int)(u32)(unsigned short)f2bs(o_ * tanhf_(creg0));
            int other = __shfl_xor(us, 16);    // q <-> q^1 (col pair partner)
            if (pubLane) {
                u32 pa = (u32)us | ((u32)other << 16);
                sys_store_u64(C0 + pubslot, ((u64)(u32)(k + 1) << 32) | (u64)pa);
            }
        }

        // ---- MID staging: h1 (check prefetched snapshot; reload-all fallback) ----
        if (k >= 1) {
            bool ok = true;
            #pragma unroll
            for (int i = 0; i < 8; i++) ok = ok && ((u32)(v1[i] >> 32) == (u32)k);
            int guard = 0;
            while (!ok && guard < 16384) {
                ok = true;
                #pragma unroll
                for (int i = 0; i < 8; i++) v1[i] = sys_load_u64(P1 + i * 256 + tid);
                #pragma unroll
                for (int i = 0; i < 8; i++) ok = ok && ((u32)(v1[i] >> 32) == (u32)k);
                guard++;
            }
            u32* dst = hs1[par];
            #pragma unroll
            for (int i = 0; i < 8; i++) { int s = i * 256 + tid; dst[(s >> 7) * 132 + (s & 127)] = (u32)v1[i]; }
        }
        __syncthreads();                       // B2

        // ---- h1 B-frags ----
        bf16x8 hb1[8];
        {
            const unsigned short* b1p = (const unsigned short*)hs1[par];
            #pragma unroll
            for (int kk = 0; kk < 8; kk++)
                hb1[kk] = *(const bf16x8*)(b1p + ln * 264 + kk * 32 + q * 8);
        }

        // ---- layer 1, step k-1: two independent acc chains (8+8 pipelined) ----
        u32 pa1 = 0; bool pub1 = false;
        if (k >= 1 && k <= SEQ) {
            f32x4 accA = {0.f, 0.f, 0.f, 0.f};
            f32x4 accB = {0.f, 0.f, 0.f, 0.f};
            #pragma unroll
            for (int kk = 0; kk < 8; kk++) {
                accA = __builtin_amdgcn_mfma_f32_16x16x32_bf16(wf[1][kk], hb0[kk], accA, 0, 0, 0);
                accB = __builtin_amdgcn_mfma_f32_16x16x32_bf16(wf[2][kk], hb1[kk], accB, 0, 0, 0);
            }
            float i_ = sigm(accA[0] + accB[0] + gxr1[0]);
            float f_ = sigm(accA[1] + accB[1] + gxr1[1]);
            float g_ = tanhf_(accA[2] + accB[2] + gxr1[2]);
            float o_ = sigm(accA[3] + accB[3] + gxr1[3]);
            creg1 = f_ * creg1 + i_ * g_;
            int us = (int)(u32)(unsigned short)f2bs(o_ * tanhf_(creg1));
            int other = __shfl_xor(us, 16);
            pa1 = (u32)us | ((u32)other << 16);
            pub1 = pubLane;
        }

        // ---- LATE h0 prefetch for k+1 (published at ~0.4T this iter by all
        //      wgs -> 0.4T slack). Issued BEFORE the L1 publish store so the
        //      top-of-(k+1) check's counted vmcnt excludes the store ack. ----
        if (k < SEQ) {
            #pragma unroll
            for (int i = 0; i < 8; i++) v0[i] = sys_load_u64(C0 + i * 256 + tid);
        }
        __builtin_amdgcn_sched_barrier(0);     // pin: prefetch before publish store

        // ---- layer-1 publish (store younger than all poll loads) ----
        if (pub1) {
            sys_store_u64(C1 + pubslot, ((u64)(u32)(k + 1) << 32) | (u64)pa1);
        }

        // ---- output projection, step k-2 (reuses hb1 = h1_{k-2}); f32x4 store ----
        if (k >= 2 && doOut) {
            f32x4 acc = {0.f, 0.f, 0.f, 0.f};
            #pragma unroll
            for (int kk = 0; kk < 8; kk++)
                acc = __builtin_amdgcn_mfma_f32_16x16x32_bf16(wo[kk], hb1[kk], acc, 0, 0, 0);
            f32x4 res;
            #pragma unroll
            for (int r = 0; r < 4; r++) res[r] = acc[r] + bor[r];
            *(f32x4*)&out[(bg * 16 + ln) * (SEQ * OUTD) + (k - 2) * OUTD + j * 16 + q * 4] = res;
        }
    }
}

extern "C" void kernel_launch(void* const* d_in, const int* in_sizes, int n_in,
                              void* d_out, int out_size, void* d_ws, size_t ws_size,
                              hipStream_t stream) {
    const float* z     = (const float*)d_in[0];
    const float* Whid  = (const float*)d_in[1];
    const float* bhid  = (const float*)d_in[2];
    const float* Wcell = (const float*)d_in[3];
    const float* bcell = (const float*)d_in[4];
    const float* Win   = (const float*)d_in[5];
    const float* bin   = (const float*)d_in[6];
    const float* Wih0  = (const float*)d_in[7];
    const float* Whh0  = (const float*)d_in[8];
    const float* bih0  = (const float*)d_in[9];
    const float* bhh0  = (const float*)d_in[10];
    const float* Wih1  = (const float*)d_in[11];
    const float* Whh1  = (const float*)d_in[12];
    const float* bih1  = (const float*)d_in[13];
    const float* bhh1  = (const float*)d_in[14];
    const float* Wout  = (const float*)d_in[15];
    const float* bout  = (const float*)d_in[16];
    float* out = (float*)d_out;

    // workspace: 2,101,248 B total (== round-8-proven size)
    u32*   gxb0u = (u32*)d_ws;                   // [131072] bf16-pair gate biases
    float* gxb1  = (float*)(gxb0u + 131072);     // [1024]
    float* c0    = gxb1 + 1024;                  // [65536]
    float* c1    = c0 + 65536;                   // [65536]
    u64*   h0B0  = (u64*)(c1 + 65536);           // [32768] tagged pair-slots x4
    u64*   h0B1  = h0B0 + 32768;
    u64*   h1B0  = h0B1 + 32768;
    u64*   h1B1  = h1B0 + 32768;

    lstm_prologue_init<<<772, 256, 0, stream>>>(z, Whid, bhid, Wcell, bcell,
                                                bih1, bhh1, h0B1, h1B1, c0, c1, gxb1);
    lstm_prologue_gx0<<<dim3(2, 256), 256, 0, stream>>>(z, Win, bin, Wih0, bih0, bhh0, gxb0u);

    void* kargs[] = { (void*)&gxb0u, (void*)&gxb1, (void*)&c0, (void*)&c1,
                      (void*)&h0B0, (void*)&h0B1, (void*)&h1B0, (void*)&h1B1,
                      (void*)&Whh0, (void*)&Wih1, (void*)&Whh1, (void*)&Wout,
                      (void*)&bout, (void*)&out };
    hipError_t ce = hipLaunchCooperativeKernel((const void*)lstm_persistent,
                                               dim3(256), dim3(256), kargs, 0, stream);
    if (ce != hipSuccess) {
        lstm_persistent<<<256, 256, 0, stream>>>(gxb0u, gxb1, c0, c1,
                                                 h0B0, h0B1, h1B0, h1B1,
                                                 Whh0, Wih1, Whh1, Wout, bout, out);
    }
}